// Round 1
// 198.740 us; speedup vs baseline: 1.0835x; 1.0835x over previous
//
#include <hip/hip_runtime.h>
#include <hip/hip_bf16.h>

typedef __bf16 bf16;
typedef __bf16 bf16x8 __attribute__((ext_vector_type(8)));
typedef float f32x4 __attribute__((ext_vector_type(4)));

// (1/16) * log2(e): softmax scale folded into exp2
#define SM_C 0.09016994374947424f

// ---------------------------------------------------------------------------
// prep: Wq/Wk/Wv/Wo [k][n] f32 -> Wt[mat][n][k] bf16 (B-operand layout)
// ---------------------------------------------------------------------------
__global__ __launch_bounds__(256) void transpose_w(
    const float* __restrict__ Wq, const float* __restrict__ Wk,
    const float* __restrict__ Wv, const float* __restrict__ Wo,
    bf16* __restrict__ Wt)
{
    int idx = blockIdx.x * 256 + threadIdx.x;   // 1024 blocks
    int m = idx >> 16, r = idx & 65535;
    int n = r >> 8, k = r & 255;
    const float* W = (m == 0) ? Wq : (m == 1) ? Wk : (m == 2) ? Wv : Wo;
    Wt[(size_t)m * 65536 + n * 256 + k] = (bf16)W[k * 256 + n];
}

// ---------------------------------------------------------------------------
// 12-in-1 fused QKV GEMM: grid (256). Each block stages its 128x256 X tile
// (f32 -> bf16) to LDS ONCE, then computes all 12 (proj, nt) 128x64 output
// panels from it. X is fetched from HBM exactly once (no cvt_x kernel, no
// L2-reuse dependence). W panels double-buffered with register prefetch;
// one barrier per panel. Panel o base = Wt + o*16384 (o = proj*4 + nt).
// ---------------------------------------------------------------------------
__global__ __launch_bounds__(256) void qkv_gemm(
    const float* __restrict__ X, const bf16* __restrict__ Wt,
    const float* __restrict__ bq, const float* __restrict__ bk,
    const float* __restrict__ bv,
    bf16* __restrict__ Qo, bf16* __restrict__ Ko, bf16* __restrict__ Vto)
{
    __shared__ bf16 Xs[128 * 264];       // 67584 B, full-K X tile
    __shared__ bf16 Ws[2][64 * 264];     // 2 x 33792 B, W panel double buffer

    const int t    = threadIdx.x;
    const int lane = t & 63, wv = t >> 6;
    const int quad = lane >> 4, l16 = lane & 15;
    const int bm   = blockIdx.x;

    const int m0 = t >> 3;          // 0..31
    const int c0 = (t & 7) * 8;

    // ---- stage X tile: 128 x 256 f32 -> bf16 LDS (once per block)
#pragma unroll
    for (int p = 0; p < 4; ++p) {
#pragma unroll
        for (int kt = 0; kt < 4; ++kt) {
            const float* px = X + (size_t)(bm * 128 + m0 + p * 32) * 256 + kt * 64 + c0;
            f32x4 a = *(const f32x4*)px, b = *(const f32x4*)(px + 4);
            bf16x8 r;
#pragma unroll
            for (int j = 0; j < 4; ++j) { r[j] = (bf16)a[j]; r[j + 4] = (bf16)b[j]; }
            *(bf16x8*)(Xs + (m0 + p * 32) * 264 + kt * 64 + c0) = r;
        }
    }

    // ---- W panel staging split: per thread 8 x 16B chunks
    const int w0 = t >> 2;          // 0..63
    const int wc = (t & 3) * 8;

    bf16x8 wreg[8];
#pragma unroll
    for (int c = 0; c < 8; ++c)     // load panel 0
        wreg[c] = *(const bf16x8*)(Wt + (size_t)w0 * 256 + c * 32 + wc);
#pragma unroll
    for (int c = 0; c < 8; ++c)     // commit panel 0 to buf 0
        *(bf16x8*)(Ws[0] + w0 * 264 + c * 32 + wc) = wreg[c];
#pragma unroll
    for (int c = 0; c < 8; ++c)     // issue panel 1 loads (in flight)
        wreg[c] = *(const bf16x8*)(Wt + (size_t)16384 + w0 * 256 + c * 32 + wc);

    for (int o = 0; o < 12; ++o) {
        __syncthreads();            // panel o visible; prior reads of buf^1 done

        if (o < 11) {               // commit panel o+1 (loads issued 1 iter ago)
#pragma unroll
            for (int c = 0; c < 8; ++c)
                *(bf16x8*)(Ws[(o + 1) & 1] + w0 * 264 + c * 32 + wc) = wreg[c];
            if (o < 10) {           // issue panel o+2 loads
#pragma unroll
                for (int c = 0; c < 8; ++c)
                    wreg[c] = *(const bf16x8*)(Wt + (size_t)(o + 2) * 16384 + w0 * 256 + c * 32 + wc);
            }
        }

        const bf16* Wb = Ws[o & 1];
        const f32x4 zero = {0.0f, 0.0f, 0.0f, 0.0f};
        f32x4 acc[2][4];
        for (int i = 0; i < 2; ++i)
            for (int j = 0; j < 4; ++j) acc[i][j] = zero;

#pragma unroll
        for (int ks = 0; ks < 8; ++ks) {
            bf16x8 a[2], bb[4];
#pragma unroll
            for (int mt = 0; mt < 2; ++mt)
                a[mt] = *(const bf16x8*)(Xs + (wv * 32 + mt * 16 + l16) * 264 + ks * 32 + quad * 8);
#pragma unroll
            for (int nt = 0; nt < 4; ++nt)
                bb[nt] = *(const bf16x8*)(Wb + (nt * 16 + l16) * 264 + ks * 32 + quad * 8);
#pragma unroll
            for (int mt = 0; mt < 2; ++mt)
#pragma unroll
                for (int nt = 0; nt < 4; ++nt)
                    acc[mt][nt] = __builtin_amdgcn_mfma_f32_16x16x32_bf16(
                        a[mt], bb[nt], acc[mt][nt], 0, 0, 0);
        }

        const int proj = o >> 2, nt4 = o & 3;
        const float* bias = (proj == 0) ? bq : (proj == 1) ? bk : bv;
#pragma unroll
        for (int nt = 0; nt < 4; ++nt) {
            int col = nt4 * 64 + nt * 16 + l16;
            float bvv = bias[col];
#pragma unroll
            for (int mt = 0; mt < 2; ++mt) {
#pragma unroll
                for (int r = 0; r < 4; ++r) {
                    int grow = bm * 128 + wv * 32 + mt * 16 + quad * 4 + r;
                    float v = acc[mt][nt][r] + bvv;
                    if (proj == 0) {
                        Qo[(size_t)grow * 256 + col] = (bf16)v;
                    } else if (proj == 1) {
                        Ko[(size_t)grow * 256 + col] = (bf16)v;
                    } else {
                        int b = grow >> 10, m = grow & 1023;
                        Vto[(size_t)b * 262144 + (size_t)col * 1024 + m] = (bf16)v;
                    }
                }
            }
        }
    }
}

// ---------------------------------------------------------------------------
// Flash attention: grid (32 b, 8 qt) — batch-major ids keep K/V L2-resident
// per XCD. Double-buffered K/V LDS -> ONE barrier per KV tile (was 2):
// stores of tile j+1 land exactly one barrier after the last reads of that
// buffer. Stores placed after the QK MFMAs; their vmcnt drain covers loads
// issued a full iteration earlier (never stalls). P tile is unpadded
// [32][32] with XOR swizzle (byte ^= (row&7)<<4): reads hit 32 distinct
// 16B slots (perfect), writes drop to 2-way.
// ---------------------------------------------------------------------------
__global__ __launch_bounds__(256, 1) void flash_attn(
    const bf16* __restrict__ Qr, const bf16* __restrict__ K,
    const bf16* __restrict__ Vt, bf16* __restrict__ A)
{
    __shared__ bf16 Ks[2][32 * 264];   // [buf][kv][c], pad 256->264
    __shared__ bf16 Vs[2][256 * 40];   // [buf][c][kv], pad 32->40
    __shared__ bf16 Ps[4][32 * 32];    // per-wave P tile, XOR-swizzled

    const int t    = threadIdx.x;
    const int lane = t & 63, wv = t >> 6;
    const int quad = lane >> 4, l16 = lane & 15;
    const int b  = blockIdx.x;   // 0..31  (fastest -> XCD = b % 8)
    const int qt = blockIdx.y;   // 0..7

    // Q fragments: A[m = lane&15][k = quad*8+j]
    bf16x8 qf[2][8];
#pragma unroll
    for (int mt = 0; mt < 2; ++mt) {
        const size_t qrow = (size_t)b * 1024 + qt * 128 + wv * 32 + mt * 16 + l16;
#pragma unroll
        for (int ks = 0; ks < 8; ++ks)
            qf[mt][ks] = *(const bf16x8*)(Qr + qrow * 256 + ks * 32 + quad * 8);
    }

    const f32x4 zero = {0.0f, 0.0f, 0.0f, 0.0f};
    f32x4 o[2][16];
    for (int mt = 0; mt < 2; ++mt)
        for (int n = 0; n < 16; ++n) o[mt][n] = zero;
    float lst[2][4] = {{0.f, 0.f, 0.f, 0.f}, {0.f, 0.f, 0.f, 0.f}};

    char* Pb = (char*)(Ps[wv]);

    // staging index split (256 threads)
    const int kv0 = t >> 5, kc0 = (t & 31) * 8;   // K: 4 x 16B per thread
    const int vc0 = t >> 2, vm0 = (t & 3) * 8;    // V: 4 x 16B per thread

    bf16x8 kp[4], vp[4];
    // prologue: tile 0 -> buf 0; tile 1 loads in flight
#pragma unroll
    for (int p = 0; p < 4; ++p) {
        kp[p] = *(const bf16x8*)(K + (size_t)(b * 1024 + kv0 + p * 8) * 256 + kc0);
        vp[p] = *(const bf16x8*)(Vt + (size_t)b * 262144 + (size_t)(vc0 + p * 64) * 1024 + vm0);
    }
#pragma unroll
    for (int p = 0; p < 4; ++p) {
        *(bf16x8*)(Ks[0] + (kv0 + p * 8) * 264 + kc0) = kp[p];
        *(bf16x8*)(Vs[0] + (vc0 + p * 64) * 40 + vm0) = vp[p];
    }
#pragma unroll
    for (int p = 0; p < 4; ++p) {
        kp[p] = *(const bf16x8*)(K + (size_t)(b * 1024 + 32 + kv0 + p * 8) * 256 + kc0);
        vp[p] = *(const bf16x8*)(Vt + (size_t)b * 262144 + (size_t)(vc0 + p * 64) * 1024 + 32 + vm0);
    }

    for (int j = 0; j < 32; ++j) {
        const bf16* Kb = Ks[j & 1];
        const bf16* Vb = Vs[j & 1];
        __syncthreads();   // tile j stores visible; prior reads of buf^1 done

        // ---- S = Q K^T : B-frag loaded once, used by both mt
        f32x4 s[2][2];
        s[0][0] = zero; s[0][1] = zero; s[1][0] = zero; s[1][1] = zero;
#pragma unroll
        for (int ks = 0; ks < 8; ++ks) {
#pragma unroll
            for (int n = 0; n < 2; ++n) {
                bf16x8 bfr = *(const bf16x8*)(Kb + (n * 16 + l16) * 264 + ks * 32 + quad * 8);
                s[0][n] = __builtin_amdgcn_mfma_f32_16x16x32_bf16(qf[0][ks], bfr, s[0][n], 0, 0, 0);
                s[1][n] = __builtin_amdgcn_mfma_f32_16x16x32_bf16(qf[1][ks], bfr, s[1][n], 0, 0, 0);
            }
        }

        // ---- commit tile j+1 into other buffer; issue tile j+2 loads
        if (j < 31) {
            bf16* Kn = Ks[(j + 1) & 1];
            bf16* Vn = Vs[(j + 1) & 1];
#pragma unroll
            for (int p = 0; p < 4; ++p) {
                *(bf16x8*)(Kn + (kv0 + p * 8) * 264 + kc0) = kp[p];
                *(bf16x8*)(Vn + (vc0 + p * 64) * 40 + vm0) = vp[p];
            }
            if (j < 30) {
#pragma unroll
                for (int p = 0; p < 4; ++p) {
                    kp[p] = *(const bf16x8*)(K + (size_t)(b * 1024 + (j + 2) * 32 + kv0 + p * 8) * 256 + kc0);
                    vp[p] = *(const bf16x8*)(Vt + (size_t)b * 262144 + (size_t)(vc0 + p * 64) * 1024 + (j + 2) * 32 + vm0);
                }
            }
        }

        // ---- no-max softmax: p = exp2(s*SM_C); P -> XOR-swizzled LDS
#pragma unroll
        for (int mt = 0; mt < 2; ++mt) {
#pragma unroll
            for (int n = 0; n < 2; ++n) {
#pragma unroll
                for (int r = 0; r < 4; ++r) {
                    float pv = __builtin_amdgcn_exp2f(s[mt][n][r] * SM_C);
                    lst[mt][r] += pv;
                    int row = mt * 16 + quad * 4 + r;
                    *(bf16*)(Pb + ((row * 64 + n * 32 + l16 * 2) ^ ((row & 7) << 4))) = (bf16)pv;
                }
            }
        }

        // ---- O += P V : V-frag loaded once, used by both mt
        bf16x8 af0 = *(const bf16x8*)(Pb + ((l16 * 64 + quad * 16) ^ ((l16 & 7) << 4)));
        bf16x8 af1 = *(const bf16x8*)(Pb + (((16 + l16) * 64 + quad * 16) ^ ((l16 & 7) << 4)));
#pragma unroll
        for (int n = 0; n < 16; ++n) {
            bf16x8 bfr = *(const bf16x8*)(Vb + (n * 16 + l16) * 40 + quad * 8);
            o[0][n] = __builtin_amdgcn_mfma_f32_16x16x32_bf16(af0, bfr, o[0][n], 0, 0, 0);
            o[1][n] = __builtin_amdgcn_mfma_f32_16x16x32_bf16(af1, bfr, o[1][n], 0, 0, 0);
        }
    }

    // ---- epilogue: reduce l across the 16-lane col group, normalize, store
#pragma unroll
    for (int mt = 0; mt < 2; ++mt) {
#pragma unroll
        for (int r = 0; r < 4; ++r) {
            float l = lst[mt][r];
            for (int off = 1; off < 16; off <<= 1)
                l += __shfl_xor(l, off, 64);
            float inv = 1.0f / l;
            size_t grow = (size_t)b * 1024 + qt * 128 + wv * 32 + mt * 16 + quad * 4 + r;
#pragma unroll
            for (int n = 0; n < 16; ++n)
                A[grow * 256 + n * 16 + l16] = (bf16)(o[mt][n][r] * inv);
        }
    }
}

// ---------------------------------------------------------------------------
// O-projection: attended bf16 x pre-transposed Wo(bf16) -> f32 out.
// grid (256 bm, 4 nt). Register-prefetch pipeline across the 4 BK=64 steps.
// ---------------------------------------------------------------------------
__global__ __launch_bounds__(256) void oproj_gemm(
    const bf16* __restrict__ Xv, const bf16* __restrict__ W,
    const float* __restrict__ bias, float* __restrict__ outv)
{
    __shared__ bf16 Xs[128 * 72];
    __shared__ bf16 Ws[64 * 72];

    const int t    = threadIdx.x;
    const int lane = t & 63, wv = t >> 6;
    const int quad = lane >> 4, l16 = lane & 15;
    const int bm = blockIdx.x;
    const int bn = blockIdx.y;

    const f32x4 zero = {0.0f, 0.0f, 0.0f, 0.0f};
    f32x4 acc[2][4];
    for (int i = 0; i < 2; ++i)
        for (int j = 0; j < 4; ++j) acc[i][j] = zero;

    const int m0 = t >> 3;
    const int c0 = (t & 7) * 8;

    bf16x8 xp[4], wp[2];
#pragma unroll
    for (int p = 0; p < 4; ++p)
        xp[p] = *(const bf16x8*)(Xv + (size_t)(bm * 128 + m0 + p * 32) * 256 + c0);
#pragma unroll
    for (int p = 0; p < 2; ++p)
        wp[p] = *(const bf16x8*)(W + (size_t)(bn * 64 + m0 + p * 32) * 256 + c0);

    for (int kt = 0; kt < 4; ++kt) {
#pragma unroll
        for (int p = 0; p < 4; ++p)
            *(bf16x8*)(Xs + (m0 + p * 32) * 72 + c0) = xp[p];
#pragma unroll
        for (int p = 0; p < 2; ++p)
            *(bf16x8*)(Ws + (m0 + p * 32) * 72 + c0) = wp[p];
        __syncthreads();

        if (kt < 3) {
#pragma unroll
            for (int p = 0; p < 4; ++p)
                xp[p] = *(const bf16x8*)(Xv + (size_t)(bm * 128 + m0 + p * 32) * 256 + (kt + 1) * 64 + c0);
#pragma unroll
            for (int p = 0; p < 2; ++p)
                wp[p] = *(const bf16x8*)(W + (size_t)(bn * 64 + m0 + p * 32) * 256 + (kt + 1) * 64 + c0);
        }

#pragma unroll
        for (int ks = 0; ks < 2; ++ks) {
            bf16x8 a[2], bb[4];
            for (int mt = 0; mt < 2; ++mt)
                a[mt] = *(const bf16x8*)(Xs + (wv * 32 + mt * 16 + l16) * 72 + ks * 32 + quad * 8);
            for (int nt = 0; nt < 4; ++nt)
                bb[nt] = *(const bf16x8*)(Ws + (nt * 16 + l16) * 72 + ks * 32 + quad * 8);
            for (int mt = 0; mt < 2; ++mt)
                for (int nt = 0; nt < 4; ++nt)
                    acc[mt][nt] = __builtin_amdgcn_mfma_f32_16x16x32_bf16(
                        a[mt], bb[nt], acc[mt][nt], 0, 0, 0);
        }
        __syncthreads();
    }

#pragma unroll
    for (int nt = 0; nt < 4; ++nt) {
        int col = bn * 64 + nt * 16 + l16;
        float bvv = bias[col];
#pragma unroll
        for (int mt = 0; mt < 2; ++mt)
#pragma unroll
            for (int r = 0; r < 4; ++r) {
                int grow = bm * 128 + wv * 32 + mt * 16 + quad * 4 + r;
                outv[(size_t)grow * 256 + col] = acc[mt][nt][r] + bvv;
            }
    }
}

// ---------------------------------------------------------------------------
extern "C" void kernel_launch(void* const* d_in, const int* in_sizes, int n_in,
                              void* d_out, int out_size, void* d_ws, size_t ws_size,
                              hipStream_t stream)
{
    (void)in_sizes; (void)n_in; (void)out_size; (void)ws_size;
    const float* X  = (const float*)d_in[0];
    const float* Wq = (const float*)d_in[1];
    const float* bq = (const float*)d_in[2];
    const float* Wk = (const float*)d_in[3];
    const float* bk = (const float*)d_in[4];
    const float* Wv = (const float*)d_in[5];
    const float* bv = (const float*)d_in[6];
    const float* Wo = (const float*)d_in[7];
    const float* bo = (const float*)d_in[8];
    float* out = (float*)d_out;

    const size_t NTOK = (size_t)32768 * 256;

    // workspace: Wt (4 mats = 512 KB) + Q + K + Vt
    bf16* Wt  = (bf16*)d_ws;
    bf16* Qw  = (bf16*)d_ws + 262144;
    bf16* Kw  = Qw + NTOK;
    bf16* Vtw = Kw + NTOK;

    transpose_w<<<1024, 256, 0, stream>>>(Wq, Wk, Wv, Wo, Wt);
    qkv_gemm   <<<256,  256, 0, stream>>>(X, Wt, bq, bk, bv, Qw, Kw, Vtw);
    flash_attn <<<dim3(32, 8),  256, 0, stream>>>(Qw, Kw, Vtw, Qw);  // in-place
    oproj_gemm <<<dim3(256, 4), 256, 0, stream>>>(Qw, Wt + 3 * 65536, bo, out);
}

// Round 2
// 186.962 us; speedup vs baseline: 1.1517x; 1.0630x over previous
//
#include <hip/hip_runtime.h>
#include <hip/hip_bf16.h>

typedef __bf16 bf16;
typedef __bf16 bf16x8 __attribute__((ext_vector_type(8)));
typedef float f32x4 __attribute__((ext_vector_type(4)));

// (1/16) * log2(e): softmax scale folded into exp2
#define SM_C 0.09016994374947424f

// ---------------------------------------------------------------------------
// prep: Wq/Wk/Wv/Wo [k][n] f32 -> Wt[mat][n][k] bf16 (B-operand layout)
// ---------------------------------------------------------------------------
__global__ __launch_bounds__(256) void transpose_w(
    const float* __restrict__ Wq, const float* __restrict__ Wk,
    const float* __restrict__ Wv, const float* __restrict__ Wo,
    bf16* __restrict__ Wt)
{
    int idx = blockIdx.x * 256 + threadIdx.x;   // 1024 blocks
    int m = idx >> 16, r = idx & 65535;
    int n = r >> 8, k = r & 255;
    const float* W = (m == 0) ? Wq : (m == 1) ? Wk : (m == 2) ? Wv : Wo;
    Wt[(size_t)m * 65536 + n * 256 + k] = (bf16)W[k * 256 + n];
}

// ---------------------------------------------------------------------------
// 12-in-1 fused QKV GEMM, 512 threads / 8 waves (2 waves/SIMD).
// Block stages its 128x256 X tile (f32 -> bf16) to LDS once, then computes
// all 12 (proj, nt) 128x64 output panels. Each wave owns 16 rows x 64 cols
// per panel. W panels double-buffered with register prefetch; one barrier
// per panel. X/W staging: lane-consecutive 32B/16B chunks (coalesced,
// LDS start bank = 4*(lane&7) -> conflict-free).
// ---------------------------------------------------------------------------
__global__ __launch_bounds__(512, 2) void qkv_gemm(
    const float* __restrict__ X, const bf16* __restrict__ Wt,
    const float* __restrict__ bq, const float* __restrict__ bk,
    const float* __restrict__ bv,
    bf16* __restrict__ Qo, bf16* __restrict__ Ko, bf16* __restrict__ Vto)
{
    __shared__ bf16 Xs[128 * 264];       // 67584 B, full-K X tile
    __shared__ bf16 Ws[2][64 * 264];     // 2 x 33792 B, W panel double buffer

    const int t    = threadIdx.x;
    const int lane = t & 63, wv = t >> 6;          // wv 0..7
    const int quad = lane >> 4, l16 = lane & 15;
    const int bm   = blockIdx.x;

    // ---- stage X tile: 128 x 256 f32 -> bf16 LDS (once per block)
    //      chunk c = t + i*512 -> row c>>5, col f32 (c&31)*8 (coalesced 32B)
#pragma unroll
    for (int i = 0; i < 8; ++i) {
        int c = t + i * 512;
        int row = c >> 5, cf = (c & 31) * 8;
        const float* px = X + (size_t)(bm * 128 + row) * 256 + cf;
        f32x4 a = *(const f32x4*)px, b = *(const f32x4*)(px + 4);
        bf16x8 r;
#pragma unroll
        for (int j = 0; j < 4; ++j) { r[j] = (bf16)a[j]; r[j + 4] = (bf16)b[j]; }
        *(bf16x8*)(Xs + row * 264 + cf) = r;
    }

    // ---- W panel staging: chunk c = t + i*512 -> row c>>5, elem (c&31)*8
    bf16x8 wreg[4];
#pragma unroll
    for (int i = 0; i < 4; ++i) {        // load panel 0
        int c = t + i * 512;
        wreg[i] = *(const bf16x8*)(Wt + (size_t)(c >> 5) * 256 + (c & 31) * 8);
    }
#pragma unroll
    for (int i = 0; i < 4; ++i) {        // commit panel 0 to buf 0
        int c = t + i * 512;
        *(bf16x8*)(Ws[0] + (c >> 5) * 264 + (c & 31) * 8) = wreg[i];
    }
#pragma unroll
    for (int i = 0; i < 4; ++i) {        // issue panel 1 loads (in flight)
        int c = t + i * 512;
        wreg[i] = *(const bf16x8*)(Wt + (size_t)16384 + (c >> 5) * 256 + (c & 31) * 8);
    }

    for (int o = 0; o < 12; ++o) {
        __syncthreads();            // panel o visible; prior reads of buf^1 done

        if (o < 11) {               // commit panel o+1 (loads issued 1 iter ago)
#pragma unroll
            for (int i = 0; i < 4; ++i) {
                int c = t + i * 512;
                *(bf16x8*)(Ws[(o + 1) & 1] + (c >> 5) * 264 + (c & 31) * 8) = wreg[i];
            }
            if (o < 10) {           // issue panel o+2 loads
#pragma unroll
                for (int i = 0; i < 4; ++i) {
                    int c = t + i * 512;
                    wreg[i] = *(const bf16x8*)(Wt + (size_t)(o + 2) * 16384 + (c >> 5) * 256 + (c & 31) * 8);
                }
            }
        }

        const bf16* Wb = Ws[o & 1];
        const f32x4 zero = {0.0f, 0.0f, 0.0f, 0.0f};
        f32x4 acc[4];
        acc[0] = zero; acc[1] = zero; acc[2] = zero; acc[3] = zero;

#pragma unroll
        for (int ks = 0; ks < 8; ++ks) {
            bf16x8 a = *(const bf16x8*)(Xs + (wv * 16 + l16) * 264 + ks * 32 + quad * 8);
#pragma unroll
            for (int nt = 0; nt < 4; ++nt) {
                bf16x8 bb = *(const bf16x8*)(Wb + (nt * 16 + l16) * 264 + ks * 32 + quad * 8);
                acc[nt] = __builtin_amdgcn_mfma_f32_16x16x32_bf16(a, bb, acc[nt], 0, 0, 0);
            }
        }

        const int proj = o >> 2, nt4 = o & 3;
        const float* bias = (proj == 0) ? bq : (proj == 1) ? bk : bv;
#pragma unroll
        for (int nt = 0; nt < 4; ++nt) {
            int col = nt4 * 64 + nt * 16 + l16;
            float bvv = bias[col];
#pragma unroll
            for (int r = 0; r < 4; ++r) {
                int grow = bm * 128 + wv * 16 + quad * 4 + r;
                float v = acc[nt][r] + bvv;
                if (proj == 0) {
                    Qo[(size_t)grow * 256 + col] = (bf16)v;
                } else if (proj == 1) {
                    Ko[(size_t)grow * 256 + col] = (bf16)v;
                } else {
                    int b = grow >> 10, m = grow & 1023;
                    Vto[(size_t)b * 262144 + (size_t)col * 1024 + m] = (bf16)v;
                }
            }
        }
    }
}

// ---------------------------------------------------------------------------
// Flash attention, 512 threads / 8 waves (2 waves/SIMD), grid (32 b, 8 qt).
// Each wave owns 16 q-rows; one shared K/V LDS copy feeds all 8 waves.
// Double-buffered K/V -> ONE barrier per KV tile; stores of tile j+1 land
// one barrier after the last reads of that buffer; loads for tile j+2
// issued right after (latency hidden under MFMA of following iters).
// P tile per wave [16][32] bf16, XOR-swizzled (byte ^= (row&7)<<4).
// ---------------------------------------------------------------------------
__global__ __launch_bounds__(512, 2) void flash_attn(
    const bf16* __restrict__ Qr, const bf16* __restrict__ K,
    const bf16* __restrict__ Vt, bf16* __restrict__ A)
{
    __shared__ bf16 Ks[2][32 * 264];   // [buf][kv][c], pad 256->264
    __shared__ bf16 Vs[2][256 * 40];   // [buf][c][kv], pad 32->40
    __shared__ bf16 Ps[8][16 * 32];    // per-wave P tile, XOR-swizzled

    const int t    = threadIdx.x;
    const int lane = t & 63, wv = t >> 6;          // wv 0..7
    const int quad = lane >> 4, l16 = lane & 15;
    const int b  = blockIdx.x;   // 0..31  (fastest -> XCD = b % 8)
    const int qt = blockIdx.y;   // 0..7

    // Q fragments: wave rows = qt*128 + wv*16 + l16
    bf16x8 qf[8];
    const size_t qrow = (size_t)b * 1024 + qt * 128 + wv * 16 + l16;
#pragma unroll
    for (int ks = 0; ks < 8; ++ks)
        qf[ks] = *(const bf16x8*)(Qr + qrow * 256 + ks * 32 + quad * 8);

    const f32x4 zero = {0.0f, 0.0f, 0.0f, 0.0f};
    f32x4 o[16];
#pragma unroll
    for (int n = 0; n < 16; ++n) o[n] = zero;
    float lst[4] = {0.f, 0.f, 0.f, 0.f};

    char* Pb = (char*)(Ps[wv]);

    // staging index split (512 threads, 2 x 16B each for K and V)
    const int kv0 = t >> 4, kc0 = (t & 15) * 8;   // K: row kv0, elems kc0 + p*128
    const int vc0 = t >> 1, vm0 = (t & 1) * 8;    // V: row vc0, elems vm0 + p*16

    bf16x8 kp[2], vp[2];
    // prologue: tile 0 -> buf 0; tile 1 loads in flight
#pragma unroll
    for (int p = 0; p < 2; ++p) {
        kp[p] = *(const bf16x8*)(K + (size_t)(b * 1024 + kv0) * 256 + kc0 + p * 128);
        vp[p] = *(const bf16x8*)(Vt + (size_t)b * 262144 + (size_t)vc0 * 1024 + vm0 + p * 16);
    }
#pragma unroll
    for (int p = 0; p < 2; ++p) {
        *(bf16x8*)(Ks[0] + kv0 * 264 + kc0 + p * 128) = kp[p];
        *(bf16x8*)(Vs[0] + vc0 * 40 + vm0 + p * 16) = vp[p];
    }
#pragma unroll
    for (int p = 0; p < 2; ++p) {
        kp[p] = *(const bf16x8*)(K + (size_t)(b * 1024 + 32 + kv0) * 256 + kc0 + p * 128);
        vp[p] = *(const bf16x8*)(Vt + (size_t)b * 262144 + (size_t)vc0 * 1024 + 32 + vm0 + p * 16);
    }

    for (int j = 0; j < 32; ++j) {
        const bf16* Kb = Ks[j & 1];
        const bf16* Vb = Vs[j & 1];
        __syncthreads();   // tile j stores visible; prior reads of buf^1 done

        // ---- S = Q K^T
        f32x4 s[2];
        s[0] = zero; s[1] = zero;
#pragma unroll
        for (int ks = 0; ks < 8; ++ks) {
#pragma unroll
            for (int n = 0; n < 2; ++n) {
                bf16x8 bfr = *(const bf16x8*)(Kb + (n * 16 + l16) * 264 + ks * 32 + quad * 8);
                s[n] = __builtin_amdgcn_mfma_f32_16x16x32_bf16(qf[ks], bfr, s[n], 0, 0, 0);
            }
        }

        // ---- commit tile j+1 into other buffer; issue tile j+2 loads
        if (j < 31) {
            bf16* Kn = Ks[(j + 1) & 1];
            bf16* Vn = Vs[(j + 1) & 1];
#pragma unroll
            for (int p = 0; p < 2; ++p) {
                *(bf16x8*)(Kn + kv0 * 264 + kc0 + p * 128) = kp[p];
                *(bf16x8*)(Vn + vc0 * 40 + vm0 + p * 16) = vp[p];
            }
            if (j < 30) {
#pragma unroll
                for (int p = 0; p < 2; ++p) {
                    kp[p] = *(const bf16x8*)(K + (size_t)(b * 1024 + (j + 2) * 32 + kv0) * 256 + kc0 + p * 128);
                    vp[p] = *(const bf16x8*)(Vt + (size_t)b * 262144 + (size_t)vc0 * 1024 + (j + 2) * 32 + vm0 + p * 16);
                }
            }
        }

        // ---- no-max softmax: p = exp2(s*SM_C); P -> XOR-swizzled LDS
#pragma unroll
        for (int n = 0; n < 2; ++n) {
#pragma unroll
            for (int r = 0; r < 4; ++r) {
                float pv = __builtin_amdgcn_exp2f(s[n][r] * SM_C);
                lst[r] += pv;
                int row = quad * 4 + r;
                *(bf16*)(Pb + ((row * 64 + n * 32 + l16 * 2) ^ ((row & 7) << 4))) = (bf16)pv;
            }
        }

        // ---- O += P V
        bf16x8 af = *(const bf16x8*)(Pb + ((l16 * 64 + quad * 16) ^ ((l16 & 7) << 4)));
#pragma unroll
        for (int n = 0; n < 16; ++n) {
            bf16x8 bfr = *(const bf16x8*)(Vb + (n * 16 + l16) * 40 + quad * 8);
            o[n] = __builtin_amdgcn_mfma_f32_16x16x32_bf16(af, bfr, o[n], 0, 0, 0);
        }
    }

    // ---- epilogue: reduce l across the 16-lane col group, normalize, store
#pragma unroll
    for (int r = 0; r < 4; ++r) {
        float l = lst[r];
        for (int off = 1; off < 16; off <<= 1)
            l += __shfl_xor(l, off, 64);
        float inv = 1.0f / l;
        size_t grow = (size_t)b * 1024 + qt * 128 + wv * 16 + quad * 4 + r;
#pragma unroll
        for (int n = 0; n < 16; ++n)
            A[grow * 256 + n * 16 + l16] = (bf16)(o[n][r] * inv);
    }
}

// ---------------------------------------------------------------------------
// O-projection: attended bf16 x pre-transposed Wo(bf16) -> f32 out.
// grid (256 bm, 4 nt). Register-prefetch pipeline across the 4 BK=64 steps.
// ---------------------------------------------------------------------------
__global__ __launch_bounds__(256) void oproj_gemm(
    const bf16* __restrict__ Xv, const bf16* __restrict__ W,
    const float* __restrict__ bias, float* __restrict__ outv)
{
    __shared__ bf16 Xs[128 * 72];
    __shared__ bf16 Ws[64 * 72];

    const int t    = threadIdx.x;
    const int lane = t & 63, wv = t >> 6;
    const int quad = lane >> 4, l16 = lane & 15;
    const int bm = blockIdx.x;
    const int bn = blockIdx.y;

    const f32x4 zero = {0.0f, 0.0f, 0.0f, 0.0f};
    f32x4 acc[2][4];
    for (int i = 0; i < 2; ++i)
        for (int j = 0; j < 4; ++j) acc[i][j] = zero;

    const int m0 = t >> 3;
    const int c0 = (t & 7) * 8;

    bf16x8 xp[4], wp[2];
#pragma unroll
    for (int p = 0; p < 4; ++p)
        xp[p] = *(const bf16x8*)(Xv + (size_t)(bm * 128 + m0 + p * 32) * 256 + c0);
#pragma unroll
    for (int p = 0; p < 2; ++p)
        wp[p] = *(const bf16x8*)(W + (size_t)(bn * 64 + m0 + p * 32) * 256 + c0);

    for (int kt = 0; kt < 4; ++kt) {
#pragma unroll
        for (int p = 0; p < 4; ++p)
            *(bf16x8*)(Xs + (m0 + p * 32) * 72 + c0) = xp[p];
#pragma unroll
        for (int p = 0; p < 2; ++p)
            *(bf16x8*)(Ws + (m0 + p * 32) * 72 + c0) = wp[p];
        __syncthreads();

        if (kt < 3) {
#pragma unroll
            for (int p = 0; p < 4; ++p)
                xp[p] = *(const bf16x8*)(Xv + (size_t)(bm * 128 + m0 + p * 32) * 256 + (kt + 1) * 64 + c0);
#pragma unroll
            for (int p = 0; p < 2; ++p)
                wp[p] = *(const bf16x8*)(W + (size_t)(bn * 64 + m0 + p * 32) * 256 + (kt + 1) * 64 + c0);
        }

#pragma unroll
        for (int ks = 0; ks < 2; ++ks) {
            bf16x8 a[2], bb[4];
            for (int mt = 0; mt < 2; ++mt)
                a[mt] = *(const bf16x8*)(Xs + (wv * 32 + mt * 16 + l16) * 72 + ks * 32 + quad * 8);
            for (int nt = 0; nt < 4; ++nt)
                bb[nt] = *(const bf16x8*)(Ws + (nt * 16 + l16) * 72 + ks * 32 + quad * 8);
            for (int mt = 0; mt < 2; ++mt)
                for (int nt = 0; nt < 4; ++nt)
                    acc[mt][nt] = __builtin_amdgcn_mfma_f32_16x16x32_bf16(
                        a[mt], bb[nt], acc[mt][nt], 0, 0, 0);
        }
        __syncthreads();
    }

#pragma unroll
    for (int nt = 0; nt < 4; ++nt) {
        int col = bn * 64 + nt * 16 + l16;
        float bvv = bias[col];
#pragma unroll
        for (int mt = 0; mt < 2; ++mt)
#pragma unroll
            for (int r = 0; r < 4; ++r) {
                int grow = bm * 128 + wv * 32 + mt * 16 + quad * 4 + r;
                outv[(size_t)grow * 256 + col] = acc[mt][nt][r] + bvv;
            }
    }
}

// ---------------------------------------------------------------------------
extern "C" void kernel_launch(void* const* d_in, const int* in_sizes, int n_in,
                              void* d_out, int out_size, void* d_ws, size_t ws_size,
                              hipStream_t stream)
{
    (void)in_sizes; (void)n_in; (void)out_size; (void)ws_size;
    const float* X  = (const float*)d_in[0];
    const float* Wq = (const float*)d_in[1];
    const float* bq = (const float*)d_in[2];
    const float* Wk = (const float*)d_in[3];
    const float* bk = (const float*)d_in[4];
    const float* Wv = (const float*)d_in[5];
    const float* bv = (const float*)d_in[6];
    const float* Wo = (const float*)d_in[7];
    const float* bo = (const float*)d_in[8];
    float* out = (float*)d_out;

    const size_t NTOK = (size_t)32768 * 256;

    // workspace: Wt (4 mats = 512 KB) + Q + K + Vt
    bf16* Wt  = (bf16*)d_ws;
    bf16* Qw  = (bf16*)d_ws + 262144;
    bf16* Kw  = Qw + NTOK;
    bf16* Vtw = Kw + NTOK;

    transpose_w<<<1024, 256, 0, stream>>>(Wq, Wk, Wv, Wo, Wt);
    qkv_gemm   <<<256,  512, 0, stream>>>(X, Wt, bq, bk, bv, Qw, Kw, Vtw);
    flash_attn <<<dim3(32, 8),  512, 0, stream>>>(Qw, Kw, Vtw, Qw);  // in-place
    oproj_gemm <<<dim3(256, 4), 256, 0, stream>>>(Qw, Wt + 3 * 65536, bo, out);
}